// Round 1
// baseline (903.382 us; speedup 1.0000x reference)
//
#include <hip/hip_runtime.h>
#include <math.h>
#include <float.h>

// Problem constants (fixed by the reference)
#define Bn   64
#define Sn   512
#define En   128
#define Hn   128
#define G4   512     // 4*H
#define FWn  6
#define Wn   507     // S - FW + 1
#define WT   32      // windows per lstm block
#define NTILE 16     // ceil(507/32)

__device__ __forceinline__ float sigf(float x) { return 1.0f / (1.0f + expf(-x)); }

// ---------------------------------------------------------------------------
// Kernel 1: P[n][j] = embed[inputs[n]] . w_ih[j] + b_ih[j] + b_hh[j]
//   n in [0, 32768), j in [0, 512). Tiled 64x64, K=128 in two halves.
//   LDS transposed [k][row] pad 68: b128 compute reads conflict-free.
// grid (8 jtiles, 512 ntiles), block 256
// ---------------------------------------------------------------------------
__global__ void __launch_bounds__(256)
proj_kernel(const int* __restrict__ inputs, const float* __restrict__ embed,
            const float* __restrict__ w_ih, const float* __restrict__ b_ih,
            const float* __restrict__ b_hh, float* __restrict__ P)
{
    __shared__ __align__(16) float At[64][68];
    __shared__ __align__(16) float Bt[64][68];
    const int t  = threadIdx.x;
    const int n0 = blockIdx.y * 64;
    const int j0 = blockIdx.x * 64;

    // loader mapping: thread -> (row r = t>>2, quarter m = t&3)
    const int r = t >> 2;
    const int m = t & 3;
    const int token = inputs[n0 + r];
    const float* __restrict__ arow = embed + token * En;
    const float* __restrict__ brow = w_ih + (j0 + r) * En;

    const int tr = t & 15;   // n-dir
    const int tc = t >> 4;   // j-dir
    float acc[4][4];
#pragma unroll
    for (int i = 0; i < 4; ++i)
#pragma unroll
        for (int j = 0; j < 4; ++j) acc[i][j] = 0.0f;

    for (int kh = 0; kh < 2; ++kh) {
        __syncthreads();   // previous half's compute done
#pragma unroll
        for (int i = 0; i < 4; ++i) {
            const int c4 = i * 4 + m;        // 0..15 float4s in this half
            const int kb = 4 * c4;           // k-local 0..60
            float4 av = *(const float4*)(arow + kh * 64 + kb);
            float4 bv = *(const float4*)(brow + kh * 64 + kb);
            At[kb + 0][r] = av.x; At[kb + 1][r] = av.y;
            At[kb + 2][r] = av.z; At[kb + 3][r] = av.w;
            Bt[kb + 0][r] = bv.x; Bt[kb + 1][r] = bv.y;
            Bt[kb + 2][r] = bv.z; Bt[kb + 3][r] = bv.w;
        }
        __syncthreads();
#pragma unroll 8
        for (int k = 0; k < 64; ++k) {
            float4 a = *(const float4*)&At[k][tr * 4];
            float4 b = *(const float4*)&Bt[k][tc * 4];
            float av[4] = {a.x, a.y, a.z, a.w};
            float bv[4] = {b.x, b.y, b.z, b.w};
#pragma unroll
            for (int ii = 0; ii < 4; ++ii)
#pragma unroll
                for (int jj = 0; jj < 4; ++jj) acc[ii][jj] += av[ii] * bv[jj];
        }
    }

    float4 bi = *(const float4*)(b_ih + j0 + tc * 4);
    float4 bh = *(const float4*)(b_hh + j0 + tc * 4);
    const float badd[4] = {bi.x + bh.x, bi.y + bh.y, bi.z + bh.z, bi.w + bh.w};
#pragma unroll
    for (int ii = 0; ii < 4; ++ii) {
        const int n = n0 + tr * 4 + ii;
        float4 o;
        o.x = acc[ii][0] + badd[0];
        o.y = acc[ii][1] + badd[1];
        o.z = acc[ii][2] + badd[2];
        o.w = acc[ii][3] + badd[3];
        *(float4*)(P + n * G4 + j0 + tc * 4) = o;
    }
}

// ---------------------------------------------------------------------------
// Kernel 2: fused 6-step LSTM over a tile of 32 windows + max partials.
//   h in LDS [k][win] (b128 reads conflict-free), c in registers.
//   w_hh streamed L2->LDS per (chunk of 32 hidden units) x (K half),
//   rows interleaved rl = 4*ul + g so each thread reads its unit's
//   i/f/g/o rows at banks (4*ug+g+kk)%32 — conflict-free (pad 65).
// grid (64 * 16), block 256
// ---------------------------------------------------------------------------
__global__ void __launch_bounds__(256)
lstm_kernel(const float* __restrict__ P, const float* __restrict__ w_hh,
            float* __restrict__ partial)
{
    __shared__ __align__(16) float hs[128][32];   // 16 KB  h[k][win]
    __shared__ float wsm[128][65];                // 33.3 KB  w chunk [rl][kk]
    const int t    = threadIdx.x;
    const int wg   = t & 7;     // window group: 4 windows each
    const int ug   = t >> 3;    // unit-in-chunk 0..31
    const int b    = blockIdx.x >> 4;
    const int tile = blockIdx.x & 15;
    const int w0   = tile * WT;
    const float* __restrict__ Pb = P + b * Sn * G4;

    float cst[4][4];    // [wi][chunk] cell state (thread's unit per chunk)
    float hreg[4][4];   // [wi][chunk] hidden state

    // ---- step 0: h = 0, so gates = P row directly ----
#pragma unroll
    for (int ch = 0; ch < 4; ++ch) {
        const int u = ch * 32 + ug;
#pragma unroll
        for (int wi = 0; wi < 4; ++wi) {
            int s = w0 + wg * 4 + wi;           // + t0 = 0
            if (s > Sn - 1) s = Sn - 1;         // clamp (masked at max)
            const float* pr = Pb + s * G4;
            float gi = pr[u], gf = pr[128 + u], gg = pr[256 + u], go = pr[384 + u];
            (void)gf;                            // f-gate * c0(=0) drops out
            float cc = sigf(gi) * tanhf(gg);
            cst[wi][ch]  = cc;
            hreg[wi][ch] = sigf(go) * tanhf(cc);
        }
    }
#pragma unroll
    for (int ch = 0; ch < 4; ++ch) {
        const int u = ch * 32 + ug;
        float4 hv = {hreg[0][ch], hreg[1][ch], hreg[2][ch], hreg[3][ch]};
        *(float4*)&hs[u][wg * 4] = hv;
    }
    // visibility of hs guaranteed by the first __syncthreads in the step loop

    // ---- steps 1..5 ----
#pragma unroll 1
    for (int st = 1; st < FWn; ++st) {
#pragma unroll
        for (int ch = 0; ch < 4; ++ch) {
            const int u = ch * 32 + ug;
            float acc[4][4];   // [wi][gate]
#pragma unroll
            for (int wi = 0; wi < 4; ++wi) {
                int s = w0 + wg * 4 + wi + st;
                if (s > Sn - 1) s = Sn - 1;
                const float* pr = Pb + s * G4;
                acc[wi][0] = pr[u];
                acc[wi][1] = pr[128 + u];
                acc[wi][2] = pr[256 + u];
                acc[wi][3] = pr[384 + u];
            }
#pragma unroll
            for (int kh = 0; kh < 2; ++kh) {
                __syncthreads();   // prior users of wsm done; hs writes visible
                {   // load w chunk half: rl = t>>1 covers 128 rows, 2 thr/row
                    const int rl = t >> 1;
                    const int mm = t & 1;
                    const int grow = (rl & 3) * 128 + ch * 32 + (rl >> 2);
                    const float* wr = w_hh + grow * 128 + kh * 64;
#pragma unroll
                    for (int i = 0; i < 8; ++i) {
                        const int c4 = i * 2 + mm;          // 0..15
                        float4 wv = *(const float4*)(wr + 4 * c4);
                        wsm[rl][4 * c4 + 0] = wv.x;
                        wsm[rl][4 * c4 + 1] = wv.y;
                        wsm[rl][4 * c4 + 2] = wv.z;
                        wsm[rl][4 * c4 + 3] = wv.w;
                    }
                }
                __syncthreads();
                const int kbase = kh * 64;
#pragma unroll 8
                for (int kk = 0; kk < 64; ++kk) {
                    float4 hv = *(const float4*)&hs[kbase + kk][wg * 4];
                    const float* wrow = &wsm[4 * ug][kk];
                    float wv0 = wrow[0];
                    float wv1 = wrow[65];
                    float wv2 = wrow[130];
                    float wv3 = wrow[195];
                    float hvv[4] = {hv.x, hv.y, hv.z, hv.w};
#pragma unroll
                    for (int wi = 0; wi < 4; ++wi) {
                        acc[wi][0] += hvv[wi] * wv0;
                        acc[wi][1] += hvv[wi] * wv1;
                        acc[wi][2] += hvv[wi] * wv2;
                        acc[wi][3] += hvv[wi] * wv3;
                    }
                }
            }
            // gate nonlinearity + state update for this chunk's unit
#pragma unroll
            for (int wi = 0; wi < 4; ++wi) {
                float ii = sigf(acc[wi][0]);
                float ff = sigf(acc[wi][1]);
                float gg = tanhf(acc[wi][2]);
                float oo = sigf(acc[wi][3]);
                float cc = ff * cst[wi][ch] + ii * gg;
                cst[wi][ch]  = cc;
                hreg[wi][ch] = oo * tanhf(cc);
            }
        }
        if (st < FWn - 1) {
            __syncthreads();   // all chunks' reads of old h finished
#pragma unroll
            for (int ch = 0; ch < 4; ++ch) {
                const int u = ch * 32 + ug;
                float4 hv = {hreg[0][ch], hreg[1][ch], hreg[2][ch], hreg[3][ch]};
                *(float4*)&hs[u][wg * 4] = hv;
            }
        }
    }

    // ---- max over this block's windows (mask invalid), reduce over wg ----
#pragma unroll
    for (int ch = 0; ch < 4; ++ch) {
        float mv = -FLT_MAX;
#pragma unroll
        for (int wi = 0; wi < 4; ++wi) {
            const int w = w0 + wg * 4 + wi;
            float hv = (w < Wn) ? hreg[wi][ch] : -FLT_MAX;
            mv = fmaxf(mv, hv);
        }
        mv = fmaxf(mv, __shfl_xor(mv, 1));
        mv = fmaxf(mv, __shfl_xor(mv, 2));
        mv = fmaxf(mv, __shfl_xor(mv, 4));
        if (wg == 0)
            partial[(b * NTILE + tile) * 128 + ch * 32 + ug] = mv;
    }
}

// ---------------------------------------------------------------------------
// Kernel 3: feat[b][u] = max over tiles; out[b][c] = feat . fc_w[c] + fc_b[c]
// grid (64), block 128
// ---------------------------------------------------------------------------
__global__ void __launch_bounds__(128)
final_kernel(const float* __restrict__ partial, const float* __restrict__ fc_w,
             const float* __restrict__ fc_b, float* __restrict__ out)
{
    const int b = blockIdx.x;
    const int u = threadIdx.x;
    float m = -FLT_MAX;
#pragma unroll
    for (int tl = 0; tl < NTILE; ++tl)
        m = fmaxf(m, partial[(b * NTILE + tl) * 128 + u]);
    float v0 = m * fc_w[u];
    float v1 = m * fc_w[128 + u];
#pragma unroll
    for (int off = 1; off < 64; off <<= 1) {
        v0 += __shfl_xor(v0, off);
        v1 += __shfl_xor(v1, off);
    }
    __shared__ float red[2][2];
    if ((u & 63) == 0) { red[u >> 6][0] = v0; red[u >> 6][1] = v1; }
    __syncthreads();
    if (u == 0) {
        out[b * 2 + 0] = red[0][0] + red[1][0] + fc_b[0];
        out[b * 2 + 1] = red[0][1] + red[1][1] + fc_b[1];
    }
}

// ---------------------------------------------------------------------------
extern "C" void kernel_launch(void* const* d_in, const int* in_sizes, int n_in,
                              void* d_out, int out_size, void* d_ws, size_t ws_size,
                              hipStream_t stream)
{
    const int*   inputs = (const int*)d_in[0];
    // d_in[1] = lengths : unused by the reference
    const float* embed  = (const float*)d_in[2];
    const float* w_ih   = (const float*)d_in[3];
    const float* w_hh   = (const float*)d_in[4];
    const float* b_ih   = (const float*)d_in[5];
    const float* b_hh   = (const float*)d_in[6];
    const float* fc_w   = (const float*)d_in[7];
    const float* fc_b   = (const float*)d_in[8];
    float* out = (float*)d_out;

    // workspace layout: P [32768][512] f32 (67.1 MB), then partials (512 KB)
    float* P       = (float*)d_ws;
    float* partial = P + (size_t)(Bn * Sn) * G4;

    proj_kernel<<<dim3(8, (Bn * Sn) / 64), 256, 0, stream>>>(inputs, embed, w_ih, b_ih, b_hh, P);
    lstm_kernel<<<dim3(Bn * NTILE), 256, 0, stream>>>(P, w_hh, partial);
    final_kernel<<<dim3(Bn), 128, 0, stream>>>(partial, fc_w, fc_b, out);
}

// Round 2
// 213.060 us; speedup vs baseline: 4.2400x; 4.2400x over previous
//
#include <hip/hip_runtime.h>
#include <math.h>
#include <float.h>

// Problem constants (fixed by the reference)
#define Bn   64
#define Sn   512
#define En   128
#define Hn   128
#define G4   512     // 4*H
#define FWn  6
#define Wn   507     // S - FW + 1
#define NTILE 16     // 507 windows -> 16 tiles of 32

typedef __attribute__((ext_vector_type(8))) _Float16 half8;
typedef __attribute__((ext_vector_type(4))) float f32x4;

__device__ __forceinline__ float sigf(float x)  { return 1.0f / (1.0f + __expf(-x)); }
// NaN-free tanh via exp: 1 - 2/(e^{2x}+1); e->inf gives 1, e->0 gives -1.
__device__ __forceinline__ float tanh_(float x) { float e = __expf(2.0f * x); return 1.0f - 2.0f / (e + 1.0f); }

// ---------------------------------------------------------------------------
// Kernel 0: pack w_ih and w_hh (both [512][128] f32) into fp16 B-fragment
// order for mfma_f32_16x16x32_f16:
//   pack[((nt*4 + ks)*64 + lane)*8 + j] = w[nt*16 + (lane&15)][ks*32 + (lane>>4)*8 + j]
// so a lane's B-fragment load is 16 contiguous bytes (fully coalesced).
// 65536 elements each; grid 256 x 256.
// ---------------------------------------------------------------------------
__global__ void __launch_bounds__(256)
pack_w_kernel(const float* __restrict__ w_ih, const float* __restrict__ w_hh,
              _Float16* __restrict__ wih_p, _Float16* __restrict__ whh_p)
{
    const int idx = blockIdx.x * 256 + threadIdx.x;      // 0..65535
    const int j  = idx & 7;
    const int L  = (idx >> 3) & 63;
    const int ks = (idx >> 9) & 3;
    const int nt = idx >> 11;
    const int row = nt * 16 + (L & 15);
    const int col = ks * 32 + (L >> 4) * 8 + j;
    wih_p[idx] = (_Float16)w_ih[row * 128 + col];
    whh_p[idx] = (_Float16)w_hh[row * 128 + col];
}

// ---------------------------------------------------------------------------
// Kernel 1 (MFMA): P[n][c] = embed[inputs[n]] . w_ih[c] + b_ih[c] + b_hh[c]
//   32 tokens (2 M-tiles) per block, N=512 split 8 nt per wave.
//   A-fragments loaded from fp32 embed rows + cvt; B from packed fp16.
// grid 1024, block 256
// ---------------------------------------------------------------------------
__global__ void __launch_bounds__(256)
proj_kernel(const int* __restrict__ inputs, const float* __restrict__ embed,
            const _Float16* __restrict__ wih_p, const float* __restrict__ b_ih,
            const float* __restrict__ b_hh, float* __restrict__ P)
{
    const int t  = threadIdx.x;
    const int L  = t & 63;
    const int wv = t >> 6;
    const int n0 = blockIdx.x * 32;
    const int q  = L >> 4;
    const int ln = L & 15;

    // A fragments: A[m = L&15][k = q*8 + j], m-tile mt, k-tile ks
    half8 A[2][4];
#pragma unroll
    for (int mt = 0; mt < 2; ++mt) {
        const int tok = inputs[n0 + mt * 16 + ln];
        const float* __restrict__ er = embed + (size_t)tok * 128 + q * 8;
#pragma unroll
        for (int ks = 0; ks < 4; ++ks) {
            float4 e0 = *(const float4*)(er + ks * 32);
            float4 e1 = *(const float4*)(er + ks * 32 + 4);
            half8 a;
            a[0] = (_Float16)e0.x; a[1] = (_Float16)e0.y;
            a[2] = (_Float16)e0.z; a[3] = (_Float16)e0.w;
            a[4] = (_Float16)e1.x; a[5] = (_Float16)e1.y;
            a[6] = (_Float16)e1.z; a[7] = (_Float16)e1.w;
            A[mt][ks] = a;
        }
    }

#pragma unroll
    for (int nti = 0; nti < 8; ++nti) {
        const int nt = wv * 8 + nti;
        f32x4 acc0 = {0.f, 0.f, 0.f, 0.f};
        f32x4 acc1 = {0.f, 0.f, 0.f, 0.f};
#pragma unroll
        for (int ks = 0; ks < 4; ++ks) {
            half8 bf = *(const half8*)(wih_p + ((size_t)(nt * 4 + ks) * 64 + L) * 8);
            acc0 = __builtin_amdgcn_mfma_f32_16x16x32_f16(A[0][ks], bf, acc0, 0, 0, 0);
            acc1 = __builtin_amdgcn_mfma_f32_16x16x32_f16(A[1][ks], bf, acc1, 0, 0, 0);
        }
        const int col = nt * 16 + ln;
        const float bias = b_ih[col] + b_hh[col];
        // C layout: lane holds rows m = q*4 + r, col = ln (within tile)
#pragma unroll
        for (int r = 0; r < 4; ++r) {
            P[(size_t)(n0 +      q * 4 + r) * G4 + col] = acc0[r] + bias;
            P[(size_t)(n0 + 16 + q * 4 + r) * G4 + col] = acc1[r] + bias;
        }
    }
}

// ---------------------------------------------------------------------------
// Kernel 2 (MFMA LSTM): 32 windows per block, 6 steps, h in LDS pre-swizzled
// to A-fragment order (double-buffered, 1 barrier/step). C initialized from
// fp32 P rows; w_hh B-fragments streamed from packed fp16 (L2-resident).
// Wave wv owns unit-tiles {2wv, 2wv+1}; per unit-tile the 4 gate row-tiles
// are nt = g*8 + ut so each lane holds i/f/g/o of its own (window, unit).
// grid 64*16, block 256
// ---------------------------------------------------------------------------
__global__ void __launch_bounds__(256)
lstm_kernel(const float* __restrict__ P, const _Float16* __restrict__ whh_p,
            float* __restrict__ partial)
{
    __shared__ _Float16 hsA[2][4096];   // 2 x 8 KB, A-fragment order
    const int t    = threadIdx.x;
    const int L    = t & 63;
    const int wv   = t >> 6;
    const int b    = blockIdx.x >> 4;
    const int tile = blockIdx.x & 15;
    const int w0   = tile * 32;
    const float* __restrict__ Pb = P + (size_t)b * Sn * G4;
    const int q  = L >> 4;
    const int ln = L & 15;
    const int j8 = L & 7;

    float cst[2][2][4];    // [uti][mt][r]
    float hcur[2][2][4];

    // ---- step 0: h = 0 -> gates = P row; f-gate drops (c0 = 0) ----
#pragma unroll
    for (int uti = 0; uti < 2; ++uti) {
        const int u = (wv * 2 + uti) * 16 + ln;
#pragma unroll
        for (int mt = 0; mt < 2; ++mt)
#pragma unroll
            for (int r = 0; r < 4; ++r) {
                int s = w0 + mt * 16 + q * 4 + r;
                s = s < 511 ? s : 511;                 // clamp (masked at max)
                const float* pr = Pb + (size_t)s * G4;
                float cc = sigf(pr[u]) * tanh_(pr[256 + u]);
                cst[uti][mt][r]  = cc;
                hcur[uti][mt][r] = sigf(pr[384 + u]) * tanh_(cc);
            }
    }
    // scatter h -> A-frag layout, buffer 0
    {
        _Float16* buf = hsA[0];
#pragma unroll
        for (int uti = 0; uti < 2; ++uti) {
            const int ut = wv * 2 + uti;
            const int ks = ut >> 1;
            const int lamb = 16 * ((ut & 1) * 2 + (ln >> 3));
#pragma unroll
            for (int mt = 0; mt < 2; ++mt)
#pragma unroll
                for (int r = 0; r < 4; ++r)
                    buf[((mt * 4 + ks) * 64 + (q * 4 + r + lamb)) * 8 + j8] =
                        (_Float16)hcur[uti][mt][r];
        }
    }

    // ---- steps 1..5 ----
    for (int st = 1; st < FWn; ++st) {
        __syncthreads();                    // h writes of previous step visible
        const _Float16* hb = hsA[(st - 1) & 1];
        half8 A[2][4];
#pragma unroll
        for (int mt = 0; mt < 2; ++mt)
#pragma unroll
            for (int ks = 0; ks < 4; ++ks)
                A[mt][ks] = *(const half8*)(hb + ((mt * 4 + ks) * 64 + L) * 8);

#pragma unroll
        for (int uti = 0; uti < 2; ++uti) {
            const int ut = wv * 2 + uti;
            const int u  = ut * 16 + ln;
            f32x4 acc[2][4];                // [mt][gate]
            // C init from fp32 P (input projection + bias, full precision)
#pragma unroll
            for (int mt = 0; mt < 2; ++mt)
#pragma unroll
                for (int r = 0; r < 4; ++r) {
                    int s = w0 + mt * 16 + q * 4 + r + st;
                    s = s < 511 ? s : 511;
                    const float* pr = Pb + (size_t)s * G4;
#pragma unroll
                    for (int g = 0; g < 4; ++g)
                        acc[mt][g][r] = pr[g * 128 + u];
                }
#pragma unroll
            for (int ks = 0; ks < 4; ++ks) {
#pragma unroll
                for (int g = 0; g < 4; ++g) {
                    const int nt = g * 8 + ut;
                    half8 bf = *(const half8*)(whh_p + ((size_t)(nt * 4 + ks) * 64 + L) * 8);
                    acc[0][g] = __builtin_amdgcn_mfma_f32_16x16x32_f16(A[0][ks], bf, acc[0][g], 0, 0, 0);
                    acc[1][g] = __builtin_amdgcn_mfma_f32_16x16x32_f16(A[1][ks], bf, acc[1][g], 0, 0, 0);
                }
            }
            // gate nonlinearity + state update
#pragma unroll
            for (int mt = 0; mt < 2; ++mt)
#pragma unroll
                for (int r = 0; r < 4; ++r) {
                    float ii = sigf(acc[mt][0][r]);
                    float ff = sigf(acc[mt][1][r]);
                    float gg = tanh_(acc[mt][2][r]);
                    float oo = sigf(acc[mt][3][r]);
                    float cc = ff * cst[uti][mt][r] + ii * gg;
                    cst[uti][mt][r]  = cc;
                    hcur[uti][mt][r] = oo * tanh_(cc);
                }
        }
        if (st < FWn - 1) {
            _Float16* buf = hsA[st & 1];    // other buffer: no barrier needed here
#pragma unroll
            for (int uti = 0; uti < 2; ++uti) {
                const int ut = wv * 2 + uti;
                const int ks = ut >> 1;
                const int lamb = 16 * ((ut & 1) * 2 + (ln >> 3));
#pragma unroll
                for (int mt = 0; mt < 2; ++mt)
#pragma unroll
                    for (int r = 0; r < 4; ++r)
                        buf[((mt * 4 + ks) * 64 + (q * 4 + r + lamb)) * 8 + j8] =
                            (_Float16)hcur[uti][mt][r];
            }
        }
    }

    // ---- max over windows (mask invalid), reduce across quads ----
#pragma unroll
    for (int uti = 0; uti < 2; ++uti) {
        float mv = -FLT_MAX;
#pragma unroll
        for (int mt = 0; mt < 2; ++mt)
#pragma unroll
            for (int r = 0; r < 4; ++r) {
                const int w = w0 + mt * 16 + q * 4 + r;
                float hv = (w < Wn) ? hcur[uti][mt][r] : -FLT_MAX;
                mv = fmaxf(mv, hv);
            }
        mv = fmaxf(mv, __shfl_xor(mv, 16));
        mv = fmaxf(mv, __shfl_xor(mv, 32));
        if (q == 0)
            partial[(size_t)(b * NTILE + tile) * 128 + (wv * 2 + uti) * 16 + ln] = mv;
    }
}

// ---------------------------------------------------------------------------
// Kernel 3: feat[b][u] = max over tiles; out[b][c] = feat . fc_w[c] + fc_b[c]
// grid 64, block 128
// ---------------------------------------------------------------------------
__global__ void __launch_bounds__(128)
final_kernel(const float* __restrict__ partial, const float* __restrict__ fc_w,
             const float* __restrict__ fc_b, float* __restrict__ out)
{
    const int b = blockIdx.x;
    const int u = threadIdx.x;
    float m = -FLT_MAX;
#pragma unroll
    for (int tl = 0; tl < NTILE; ++tl)
        m = fmaxf(m, partial[(size_t)(b * NTILE + tl) * 128 + u]);
    float v0 = m * fc_w[u];
    float v1 = m * fc_w[128 + u];
#pragma unroll
    for (int off = 1; off < 64; off <<= 1) {
        v0 += __shfl_xor(v0, off);
        v1 += __shfl_xor(v1, off);
    }
    __shared__ float red[2][2];
    if ((u & 63) == 0) { red[u >> 6][0] = v0; red[u >> 6][1] = v1; }
    __syncthreads();
    if (u == 0) {
        out[b * 2 + 0] = red[0][0] + red[1][0] + fc_b[0];
        out[b * 2 + 1] = red[0][1] + red[1][1] + fc_b[1];
    }
}

// ---------------------------------------------------------------------------
extern "C" void kernel_launch(void* const* d_in, const int* in_sizes, int n_in,
                              void* d_out, int out_size, void* d_ws, size_t ws_size,
                              hipStream_t stream)
{
    const int*   inputs = (const int*)d_in[0];
    // d_in[1] = lengths : unused by the reference
    const float* embed  = (const float*)d_in[2];
    const float* w_ih   = (const float*)d_in[3];
    const float* w_hh   = (const float*)d_in[4];
    const float* b_ih   = (const float*)d_in[5];
    const float* b_hh   = (const float*)d_in[6];
    const float* fc_w   = (const float*)d_in[7];
    const float* fc_b   = (const float*)d_in[8];
    float* out = (float*)d_out;

    // workspace: P [32768][512] f32 (64 MiB) | partial (512 KiB) | packs (2x128 KiB)
    float*    P       = (float*)d_ws;
    float*    partial = P + (size_t)(Bn * Sn) * G4;
    _Float16* wih_p   = (_Float16*)(partial + Bn * NTILE * 128);
    _Float16* whh_p   = wih_p + 65536;

    pack_w_kernel<<<dim3(256), 256, 0, stream>>>(w_ih, w_hh, wih_p, whh_p);
    proj_kernel<<<dim3((Bn * Sn) / 32), 256, 0, stream>>>(inputs, embed, wih_p, b_ih, b_hh, P);
    lstm_kernel<<<dim3(Bn * NTILE), 256, 0, stream>>>(P, whh_p, partial);
    final_kernel<<<dim3(Bn), 128, 0, stream>>>(partial, fc_w, fc_b, out);
}